// Round 1
// baseline (874.594 us; speedup 1.0000x reference)
//
#include <hip/hip_runtime.h>

#define NN 100000
#define NE 1600000

typedef short v8s __attribute__((ext_vector_type(8)));
typedef float v4f __attribute__((ext_vector_type(4)));
typedef unsigned short v4u16 __attribute__((ext_vector_type(4)));

__device__ __forceinline__ unsigned short f2bf(float f) {
    union { float f; unsigned int u; } v; v.f = f;
    unsigned int r = v.u + 0x7FFFu + ((v.u >> 16) & 1u);  // RNE
    return (unsigned short)(r >> 16);
}

// Store 4 floats as bf16 into fragment-order LDS: element (row, k) lives at
// [ (k/32)*2048 + row*32 + (k%32) ]  (kb-major blocks of 64 rows x 32 k's).
// This makes every MFMA fragment read a contiguous, conflict-free ds_read_b128.
__device__ __forceinline__ void store_bf4(unsigned short* base, int row, int k, float4 v) {
    v4u16 p;
    p.x = f2bf(v.x); p.y = f2bf(v.y); p.z = f2bf(v.z); p.w = f2bf(v.w);
    *(v4u16*)(base + ((k >> 5) * 2048 + row * 32 + (k & 31))) = p;
}

#define MFMA16(acc, a, b) acc = __builtin_amdgcn_mfma_f32_16x16x32_bf16(a, b, acc, 0, 0, 0)

// ---------------------------------------------------------------------------
// Edge kernel: per 64-edge tile, A = concat(e, x[s], x[r]) -> 3-layer MLP ->
// atomicAdd into agg[receivers]. Persistent blocks; weights in LDS (frag layout).
// LDS: WT1 6*2048 + WT2 2*2048 + WT3 2*2048 + A 6*2048 = 32768 u16 = 64 KiB.
// ---------------------------------------------------------------------------
__global__ __launch_bounds__(256, 2) void edge_kernel(
    const float* __restrict__ x, const float* __restrict__ e,
    const int* __restrict__ snd, const int* __restrict__ rcv,
    const float* __restrict__ We1, const float* __restrict__ be1,
    const float* __restrict__ We2, const float* __restrict__ be2,
    const float* __restrict__ We3, const float* __restrict__ be3,
    float* agg, int numTiles)
{
    extern __shared__ unsigned short smem[];
    unsigned short* WT1 = smem;             // 12288 u16 (kb 0..5)
    unsigned short* WT2 = WT1 + 12288;      // 4096
    unsigned short* WT3 = WT2 + 4096;       // 4096
    unsigned short* A   = WT3 + 4096;       // 12288 (kb 0..5); H1 lives in kb0-1, H2 in kb2-3

    const int tid = threadIdx.x;

    // Stage weights once per block, transposed into frag layout: WT[kb][n][k%32]
    for (int idx = tid; idx < 192 * 64; idx += 256) {
        int k = idx >> 6, n = idx & 63;
        WT1[(k >> 5) * 2048 + n * 32 + (k & 31)] = f2bf(We1[idx]);
    }
    for (int idx = tid; idx < 64 * 64; idx += 256) {
        int k = idx >> 6, n = idx & 63;
        int off = (k >> 5) * 2048 + n * 32 + (k & 31);
        WT2[off] = f2bf(We2[idx]);
        WT3[off] = f2bf(We3[idx]);
    }

    const int lane = tid & 63;
    const int wv   = tid >> 6;          // wave 0..3 -> edge strip [16*wv, 16*wv+16)
    const int l15  = lane & 15;
    const int quad = lane >> 4;
    const int astrip = wv * 16;

    // Per-lane bias values (col = nt*16 + l15), kept in registers.
    float b1v[4], b2v[4], b3v[4];
#pragma unroll
    for (int nt = 0; nt < 4; ++nt) {
        b1v[nt] = be1[nt * 16 + l15];
        b2v[nt] = be2[nt * 16 + l15];
        b3v[nt] = be3[nt * 16 + l15];
    }

    const int arow = (astrip + l15) * 32 + quad * 8;   // a-frag offset within a kb block
    const int brow = l15 * 32 + quad * 8;              // b-frag offset (+ nt*512)

    __syncthreads();

    for (int tile = blockIdx.x; tile < numTiles; tile += gridDim.x) {
        const int ebase = tile * 64;

        // ---- Gather/stage A: rows = edges, k = [e | x[s] | x[r]] ----
#pragma unroll
        for (int t = 0; t < 4; ++t) {
            int idx = tid + t * 256;          // 0..1023
            int row = idx >> 4;
            int k0  = (idx & 15) * 4;
            float4 ve = *(const float4*)(e + (size_t)(ebase + row) * 64 + k0);
            store_bf4(A, row, k0, ve);
            int s = snd[ebase + row];
            float4 vs = *(const float4*)(x + (size_t)s * 64 + k0);
            store_bf4(A, row, 64 + k0, vs);
            int r = rcv[ebase + row];
            float4 vr = *(const float4*)(x + (size_t)r * 64 + k0);
            store_bf4(A, row, 128 + k0, vr);
        }
        __syncthreads();

        // ---- Layer 1: [64,192] @ [192,64], relu -> H1 (A kb0-1, own rows) ----
        {
            v4f acc[4];
#pragma unroll
            for (int nt = 0; nt < 4; ++nt) acc[nt] = (v4f){0.f, 0.f, 0.f, 0.f};
#pragma unroll
            for (int kb = 0; kb < 6; ++kb) {
                v8s af = *(const v8s*)(A + kb * 2048 + arow);
#pragma unroll
                for (int nt = 0; nt < 4; ++nt) {
                    v8s bf = *(const v8s*)(WT1 + kb * 2048 + brow + nt * 512);
                    MFMA16(acc[nt], af, bf);
                }
            }
#pragma unroll
            for (int nt = 0; nt < 4; ++nt) {
                int kk = nt * 16 + l15;
#pragma unroll
                for (int r = 0; r < 4; ++r) {
                    int m = astrip + quad * 4 + r;
                    float v = acc[nt][r] + b1v[nt];
                    v = v > 0.f ? v : 0.f;
                    A[(kk >> 5) * 2048 + m * 32 + (kk & 31)] = f2bf(v);
                }
            }
        }

        // ---- Layer 2: [64,64] @ [64,64], relu -> H2 (A kb2-3, own rows) ----
        {
            v4f acc[4];
#pragma unroll
            for (int nt = 0; nt < 4; ++nt) acc[nt] = (v4f){0.f, 0.f, 0.f, 0.f};
#pragma unroll
            for (int kb = 0; kb < 2; ++kb) {
                v8s af = *(const v8s*)(A + kb * 2048 + arow);
#pragma unroll
                for (int nt = 0; nt < 4; ++nt) {
                    v8s bf = *(const v8s*)(WT2 + kb * 2048 + brow + nt * 512);
                    MFMA16(acc[nt], af, bf);
                }
            }
#pragma unroll
            for (int nt = 0; nt < 4; ++nt) {
                int kk = nt * 16 + l15;
#pragma unroll
                for (int r = 0; r < 4; ++r) {
                    int m = astrip + quad * 4 + r;
                    float v = acc[nt][r] + b2v[nt];
                    v = v > 0.f ? v : 0.f;
                    A[(2 + (kk >> 5)) * 2048 + m * 32 + (kk & 31)] = f2bf(v);
                }
            }
        }

        // ---- Layer 3: [64,64] @ [64,64] (no relu) -> atomic scatter ----
        {
            v4f acc[4];
#pragma unroll
            for (int nt = 0; nt < 4; ++nt) acc[nt] = (v4f){0.f, 0.f, 0.f, 0.f};
#pragma unroll
            for (int kb = 0; kb < 2; ++kb) {
                v8s af = *(const v8s*)(A + (2 + kb) * 2048 + arow);
#pragma unroll
                for (int nt = 0; nt < 4; ++nt) {
                    v8s bf = *(const v8s*)(WT3 + kb * 2048 + brow + nt * 512);
                    MFMA16(acc[nt], af, bf);
                }
            }
#pragma unroll
            for (int r = 0; r < 4; ++r) {
                int el = astrip + quad * 4 + r;
                int dst = rcv[ebase + el];            // L1-hit (16 lanes same addr)
                float* aggrow = agg + (size_t)dst * 64;
#pragma unroll
                for (int nt = 0; nt < 4; ++nt) {
                    unsafeAtomicAdd(aggrow + nt * 16 + l15, acc[nt][r] + b3v[nt]);
                }
            }
        }
        __syncthreads();   // all waves done reading A before next tile's gather
    }
}

// ---------------------------------------------------------------------------
// Node kernel: A = concat(x, agg) [64,128] -> 3-layer MLP -> out.
// agg lives in `aggout` (same buffer as out); each block reads then overwrites
// only its own rows. LDS: 8192+4096+4096+8192 = 24576 u16 = 48 KiB.
// ---------------------------------------------------------------------------
__global__ __launch_bounds__(256, 2) void node_kernel(
    const float* __restrict__ x,
    const float* __restrict__ Wn1, const float* __restrict__ bn1,
    const float* __restrict__ Wn2, const float* __restrict__ bn2,
    const float* __restrict__ Wn3, const float* __restrict__ bn3,
    float* aggout)
{
    extern __shared__ unsigned short smem[];
    unsigned short* WT1 = smem;             // 8192 (kb 0..3)
    unsigned short* WT2 = WT1 + 8192;       // 4096
    unsigned short* WT3 = WT2 + 4096;       // 4096
    unsigned short* A   = WT3 + 4096;       // 8192 (kb 0..3); H1 kb0-1, H2 kb2-3

    const int tid = threadIdx.x;

    for (int idx = tid; idx < 128 * 64; idx += 256) {
        int k = idx >> 6, n = idx & 63;
        WT1[(k >> 5) * 2048 + n * 32 + (k & 31)] = f2bf(Wn1[idx]);
    }
    for (int idx = tid; idx < 64 * 64; idx += 256) {
        int k = idx >> 6, n = idx & 63;
        int off = (k >> 5) * 2048 + n * 32 + (k & 31);
        WT2[off] = f2bf(Wn2[idx]);
        WT3[off] = f2bf(Wn3[idx]);
    }

    const int lane = tid & 63;
    const int wv   = tid >> 6;
    const int l15  = lane & 15;
    const int quad = lane >> 4;
    const int astrip = wv * 16;

    float b1v[4], b2v[4], b3v[4];
#pragma unroll
    for (int nt = 0; nt < 4; ++nt) {
        b1v[nt] = bn1[nt * 16 + l15];
        b2v[nt] = bn2[nt * 16 + l15];
        b3v[nt] = bn3[nt * 16 + l15];
    }

    const int arow = (astrip + l15) * 32 + quad * 8;
    const int brow = l15 * 32 + quad * 8;
    const int nbase = blockIdx.x * 64;

    __syncthreads();

    // ---- Gather: A rows = nodes, k = [x | agg] ----
#pragma unroll
    for (int t = 0; t < 4; ++t) {
        int idx = tid + t * 256;
        int row = idx >> 4;
        int k0  = (idx & 15) * 4;
        int node = nbase + row;
        float4 vx = {0.f, 0.f, 0.f, 0.f}, va = {0.f, 0.f, 0.f, 0.f};
        if (node < NN) {
            vx = *(const float4*)(x + (size_t)node * 64 + k0);
            va = *(const float4*)(aggout + (size_t)node * 64 + k0);
        }
        store_bf4(A, row, k0, vx);
        store_bf4(A, row, 64 + k0, va);
    }
    __syncthreads();

    // ---- Layer 1: K=128, relu -> H1 (kb0-1) ----
    {
        v4f acc[4];
#pragma unroll
        for (int nt = 0; nt < 4; ++nt) acc[nt] = (v4f){0.f, 0.f, 0.f, 0.f};
#pragma unroll
        for (int kb = 0; kb < 4; ++kb) {
            v8s af = *(const v8s*)(A + kb * 2048 + arow);
#pragma unroll
            for (int nt = 0; nt < 4; ++nt) {
                v8s bf = *(const v8s*)(WT1 + kb * 2048 + brow + nt * 512);
                MFMA16(acc[nt], af, bf);
            }
        }
#pragma unroll
        for (int nt = 0; nt < 4; ++nt) {
            int kk = nt * 16 + l15;
#pragma unroll
            for (int r = 0; r < 4; ++r) {
                int m = astrip + quad * 4 + r;
                float v = acc[nt][r] + b1v[nt];
                v = v > 0.f ? v : 0.f;
                A[(kk >> 5) * 2048 + m * 32 + (kk & 31)] = f2bf(v);
            }
        }
    }

    // ---- Layer 2: K=64, relu -> H2 (kb2-3) ----
    {
        v4f acc[4];
#pragma unroll
        for (int nt = 0; nt < 4; ++nt) acc[nt] = (v4f){0.f, 0.f, 0.f, 0.f};
#pragma unroll
        for (int kb = 0; kb < 2; ++kb) {
            v8s af = *(const v8s*)(A + kb * 2048 + arow);
#pragma unroll
            for (int nt = 0; nt < 4; ++nt) {
                v8s bf = *(const v8s*)(WT2 + kb * 2048 + brow + nt * 512);
                MFMA16(acc[nt], af, bf);
            }
        }
#pragma unroll
        for (int nt = 0; nt < 4; ++nt) {
            int kk = nt * 16 + l15;
#pragma unroll
            for (int r = 0; r < 4; ++r) {
                int m = astrip + quad * 4 + r;
                float v = acc[nt][r] + b2v[nt];
                v = v > 0.f ? v : 0.f;
                A[(2 + (kk >> 5)) * 2048 + m * 32 + (kk & 31)] = f2bf(v);
            }
        }
    }

    // ---- Layer 3: K=64, no relu -> out ----
    {
        v4f acc[4];
#pragma unroll
        for (int nt = 0; nt < 4; ++nt) acc[nt] = (v4f){0.f, 0.f, 0.f, 0.f};
#pragma unroll
        for (int kb = 0; kb < 2; ++kb) {
            v8s af = *(const v8s*)(A + (2 + kb) * 2048 + arow);
#pragma unroll
            for (int nt = 0; nt < 4; ++nt) {
                v8s bf = *(const v8s*)(WT3 + kb * 2048 + brow + nt * 512);
                MFMA16(acc[nt], af, bf);
            }
        }
#pragma unroll
        for (int r = 0; r < 4; ++r) {
            int node = nbase + astrip + quad * 4 + r;
            if (node < NN) {
#pragma unroll
                for (int nt = 0; nt < 4; ++nt) {
                    aggout[(size_t)node * 64 + nt * 16 + l15] = acc[nt][r] + b3v[nt];
                }
            }
        }
    }
}

extern "C" void kernel_launch(void* const* d_in, const int* in_sizes, int n_in,
                              void* d_out, int out_size, void* d_ws, size_t ws_size,
                              hipStream_t stream) {
    const float* x   = (const float*)d_in[0];
    const float* e   = (const float*)d_in[1];
    const int*   snd = (const int*)d_in[2];
    const int*   rcv = (const int*)d_in[3];
    const float* We1 = (const float*)d_in[4];  const float* be1 = (const float*)d_in[5];
    const float* We2 = (const float*)d_in[6];  const float* be2 = (const float*)d_in[7];
    const float* We3 = (const float*)d_in[8];  const float* be3 = (const float*)d_in[9];
    const float* Wn1 = (const float*)d_in[10]; const float* bn1 = (const float*)d_in[11];
    const float* Wn2 = (const float*)d_in[12]; const float* bn2 = (const float*)d_in[13];
    const float* Wn3 = (const float*)d_in[14]; const float* bn3 = (const float*)d_in[15];
    float* out = (float*)d_out;

    // out doubles as the agg buffer (exactly N*64 floats); zero it first.
    hipMemsetAsync(out, 0, (size_t)NN * 64 * sizeof(float), stream);

    edge_kernel<<<512, 256, 65536, stream>>>(x, e, snd, rcv,
                                             We1, be1, We2, be2, We3, be3,
                                             out, NE / 64);

    node_kernel<<<(NN + 63) / 64, 256, 49152, stream>>>(x,
                                                        Wn1, bn1, Wn2, bn2, Wn3, bn3,
                                                        out);
}